// Round 4
// baseline (879.941 us; speedup 1.0000x reference)
//
#include <hip/hip_runtime.h>
#include <hip/hip_cooperative_groups.h>
#include <stdint.h>

namespace cg = cooperative_groups;

#define NB 32
#define CC 64
#define HH 112
#define WW 112
#define HW (HH * WW)            // 12544
#define NHW (NB * HW)           // 401408
#define GRID 1024               // 4 blocks/CU on 256 CUs -> cooperative co-residency guaranteed

// ---- shared helpers ----
struct WRegs {
    uint64_t w[9];
    int corrMid, dL, dR;
};

__device__ __forceinline__ void load_wregs(WRegs& W, const uint64_t* __restrict__ wbits,
                                           int lane, int h) {
    int tc[9];
#pragma unroll
    for (int t = 0; t < 9; t++) {
        W.w[t] = wbits[lane * 9 + t];
        tc[t] = 64 - 2 * (int)__builtin_popcountll(W.w[t]);
    }
    W.corrMid = 0;
    int oL = 0, oR = 0;
    if (h == 0)      { W.corrMid = tc[0] + tc[1] + tc[2]; oL = tc[0]; oR = tc[2]; }
    if (h == HH - 1) { W.corrMid = tc[6] + tc[7] + tc[8]; oL = tc[6]; oR = tc[8]; }
    W.dL = tc[0] + tc[3] + tc[6] - oL;
    W.dR = tc[2] + tc[5] + tc[8] - oR;
}

__device__ __forceinline__ int conv_px(const uint64_t l[3], const uint64_t m[3],
                                       const uint64_t r[3], const WRegs& W) {
    int pc = 0;
#pragma unroll
    for (int rr = 0; rr < 3; rr++) {
        pc += (int)__builtin_popcountll(l[rr] ^ W.w[rr * 3 + 0]);
        pc += (int)__builtin_popcountll(m[rr] ^ W.w[rr * 3 + 1]);
        pc += (int)__builtin_popcountll(r[rr] ^ W.w[rr * 3 + 2]);
    }
    return 576 - 2 * pc - W.corrMid;
}

// ======================= MEGA KERNEL (cooperative) =======================
__global__ __launch_bounds__(256, 4) void mega_kernel(
        const float* __restrict__ x, const float* __restrict__ wflat,
        const float* __restrict__ gamma, const float* __restrict__ beta,
        float* __restrict__ out,
        uint64_t* __restrict__ bits, uint64_t* __restrict__ wbits,
        float* __restrict__ wscale, int* __restrict__ ch_sum,
        unsigned long long* __restrict__ ch_sumsq) {
    cg::grid_group grid = cg::this_grid();

    __shared__ uint64_t rowbuf[4][3][58];
    __shared__ int redS[4][64];
    __shared__ int redQ[4][64];
    __shared__ float b2s[16][65];
    __shared__ float A2s[64];

    int tid = threadIdx.x;
    int wave = tid >> 6, lane = tid & 63;
    int bid = blockIdx.x;

    // ---------- phase A: xpack (blocks 0..783) + wpack (blocks 960..1023, wave 0)
    if (bid < 784) {
        int p2 = bid * 256 + tid;                     // < NHW/2 exactly
        int n = p2 / (HW / 2);
        int r2 = p2 - n * (HW / 2);
        const float2* xp = (const float2*)(x + (size_t)n * CC * HW) + r2;
        uint64_t b0 = 0, b1 = 0;
#pragma unroll 16
        for (int c = 0; c < 64; c++) {
            float2 v = xp[(size_t)c * (HW / 2)];
            b0 |= (uint64_t)(v.x > 0.0f) << c;
            b1 |= (uint64_t)(v.y > 0.0f) << c;
        }
        ulonglong2 pr;
        pr.x = b0; pr.y = b1;
        *((ulonglong2*)(bits + (size_t)n * HW) + r2) = pr;
    } else if (bid >= 960 && wave == 0) {
        int o = bid - 960;                            // output channel
        int i = lane;                                 // input channel
        const float* wp = wflat + (size_t)(o * 64 + i) * 9;
        float w[9];
        float asum = 0.f;
#pragma unroll
        for (int t = 0; t < 9; t++) { w[t] = wp[t]; asum += fabsf(w[t]); }
#pragma unroll
        for (int s = 32; s > 0; s >>= 1) asum += __shfl_xor(asum, s, 64);
        float scale = asum * (1.0f / 576.0f);
        uint64_t b[9];
#pragma unroll
        for (int t = 0; t < 9; t++) b[t] = __ballot(w[t] >= 0.0f);
        if (i == 0) {
#pragma unroll
            for (int t = 0; t < 9; t++) wbits[o * 9 + t] = b[t];
            wscale[o] = scale;
            ch_sum[o] = 0;
            ch_sumsq[o] = 0ull;
        }
    }
    grid.sync();

    // ---------- phase B: stats (1792 virtual blocks, 4 half-row waves each)
    for (int vb = bid; vb < 1792; vb += GRID) {
        int Wid = vb * 4 + wave;                      // < 7168
        int n = __builtin_amdgcn_readfirstlane(Wid / 224);
        int rem = Wid - n * 224;
        int h = __builtin_amdgcn_readfirstlane(rem >> 1);
        int c0 = __builtin_amdgcn_readfirstlane((rem & 1) * 56);
        const uint64_t* bp = bits + (size_t)n * HW;

        for (int e = lane; e < 3 * 58; e += 64) {
            int t = e / 58, c = e - t * 58;
            int hh = h - 1 + t, ww = c0 - 1 + c;
            uint64_t v = 0;
            if (hh >= 0 && hh < HH && ww >= 0 && ww < WW) v = bp[hh * WW + ww];
            rowbuf[wave][t][c] = v;
        }
        WRegs W;
        load_wregs(W, wbits, lane, h);
        __syncthreads();

        const uint64_t(*rb)[58] = rowbuf[wave];
        int s1 = 0, s2 = 0;
        uint64_t win[3][3];
        for (int j0 = 0; j0 < 56; j0 += 14) {
#pragma unroll
            for (int rr = 0; rr < 3; rr++) { win[0][rr] = rb[rr][j0]; win[1][rr] = rb[rr][j0 + 1]; }
#pragma unroll
            for (int j = 0; j < 14; j++) {
#pragma unroll
                for (int rr = 0; rr < 3; rr++) win[(j + 2) % 3][rr] = rb[rr][j0 + j + 2];
                int S = conv_px(win[j % 3], win[(j + 1) % 3], win[(j + 2) % 3], W);
                int wpx = c0 + j0 + j;
                if (wpx == 0) S -= W.dL;
                if (wpx == WW - 1) S -= W.dR;
                s1 += S;
                s2 += S * S;
            }
        }
        redS[wave][lane] = s1;
        redQ[wave][lane] = s2;
        __syncthreads();
        if (tid < 64) {
            int t1 = redS[0][tid] + redS[1][tid] + redS[2][tid] + redS[3][tid];
            int t2 = redQ[0][tid] + redQ[1][tid] + redQ[2][tid] + redQ[3][tid];
            atomicAdd(&ch_sum[tid], t1);
            atomicAdd(&ch_sumsq[tid], (unsigned long long)(long long)t2);
        }
        __syncthreads();
    }
    grid.sync();

    // ---------- bnprep: every block computes A2/B2 redundantly into LDS
    if (tid < 64) {
        int o = tid;
        double P = (double)NHW;
        double meanS = (double)ch_sum[o] / P;
        double e2 = (double)ch_sumsq[o] / P;
        double varS = e2 - meanS * meanS;
        double sc = (double)wscale[o];
        double mean_y = sc * meanS;
        double var_y = sc * sc * varS;
        double inv = (double)gamma[o] / sqrt(var_y + 1e-5);
        float a = (float)(sc * inv);
        float b = (float)((double)beta[o] - mean_y * inv);
        A2s[o] = -2.0f * a;
        int tc[9];
#pragma unroll
        for (int t = 0; t < 9; t++) tc[t] = 64 - 2 * (int)__builtin_popcountll(wbits[o * 9 + t]);
#pragma unroll
        for (int f = 0; f < 16; f++) {
            int corr = 0;
#pragma unroll
            for (int t = 0; t < 9; t++) {
                int r = t / 3, c = t % 3;
                bool pad = ((f & 1) && r == 0) || ((f & 2) && r == 2) ||
                           ((f & 4) && c == 0) || ((f & 8) && c == 2);
                if (pad) corr += tc[t];
            }
            b2s[f][o] = (float)(576 - corr) * a + b;
        }
    }
    __syncthreads();

    // ---------- phase C: final conv + BN + residual (1568 virtual blocks)
    for (int vb = bid; vb < 1568; vb += GRID) {
        int Wid = vb * 4 + wave;                      // < 6272
        int n = __builtin_amdgcn_readfirstlane(Wid / 196);
        int p = (Wid - n * 196) * 64 + lane;          // pixel in image
        int h = p / WW;
        int w = p - h * WW;

        const uint64_t* bp = bits + (size_t)n * HW;
        uint64_t win[9];
#pragma unroll
        for (int t = 0; t < 9; t++) {
            int hh = h + (t / 3) - 1;
            int ww = w + (t % 3) - 1;
            bool valid = (hh >= 0) && (hh < HH) && (ww >= 0) && (ww < WW);
            int hc = hh < 0 ? 0 : (hh > HH - 1 ? HH - 1 : hh);
            int wc = ww < 0 ? 0 : (ww > WW - 1 ? WW - 1 : ww);
            uint64_t v = bp[hc * WW + wc];
            win[t] = valid ? v : 0ull;
        }
        int f = (h == 0 ? 1 : 0) | (h == HH - 1 ? 2 : 0) | (w == 0 ? 4 : 0) | (w == WW - 1 ? 8 : 0);
        const float* b2row = &b2s[f][0];

        uint32_t pcp[32];
#pragma unroll
        for (int o2 = 0; o2 < 32; o2++) {
            const uint64_t* wp = wbits + (o2 * 2) * 9;   // wave-uniform -> scalar loads
            int pcA = 0, pcB = 0;
#pragma unroll
            for (int t = 0; t < 9; t++) {
                pcA += (int)__builtin_popcountll(win[t] ^ wp[t]);
                pcB += (int)__builtin_popcountll(win[t] ^ wp[t + 9]);
            }
            pcp[o2] = (uint32_t)pcA | ((uint32_t)pcB << 16);
        }

        const float* xb = x + (size_t)n * CC * HW + p;
        float* ob = out + (size_t)n * CC * HW + p;
#pragma unroll
        for (int o2 = 0; o2 < 32; o2++) {
            int o0 = o2 * 2, o1 = o2 * 2 + 1;
            float pc0 = (float)(int)(pcp[o2] & 0xffffu);
            float pc1 = (float)(int)(pcp[o2] >> 16);
            float y0 = fmaf(pc0, A2s[o0], b2row[o0]) + xb[(size_t)o0 * HW];
            float y1 = fmaf(pc1, A2s[o1], b2row[o1]) + xb[(size_t)o1 * HW];
            __builtin_nontemporal_store(y0, &ob[(size_t)o0 * HW]);
            __builtin_nontemporal_store(y1, &ob[(size_t)o1 * HW]);
        }
    }
}

// ======================= fallback path (proven 5-kernel pipeline) =======================
__global__ void wpack_kernel(const float* __restrict__ wflat,
                             uint64_t* __restrict__ wbits,
                             float* __restrict__ wscale,
                             int* __restrict__ ch_sum,
                             unsigned long long* __restrict__ ch_sumsq) {
    int o = blockIdx.x;
    int i = threadIdx.x;
    const float* wp = wflat + (size_t)(o * 64 + i) * 9;
    float w[9];
    float asum = 0.f;
#pragma unroll
    for (int t = 0; t < 9; t++) { w[t] = wp[t]; asum += fabsf(w[t]); }
#pragma unroll
    for (int s = 32; s > 0; s >>= 1) asum += __shfl_xor(asum, s, 64);
    float scale = asum * (1.0f / 576.0f);
    uint64_t b[9];
#pragma unroll
    for (int t = 0; t < 9; t++) b[t] = __ballot(w[t] >= 0.0f);
    if (i == 0) {
#pragma unroll
        for (int t = 0; t < 9; t++) wbits[o * 9 + t] = b[t];
        wscale[o] = scale;
        ch_sum[o] = 0;
        ch_sumsq[o] = 0ull;
    }
}

__global__ __launch_bounds__(256) void xpack2_kernel(const float* __restrict__ x,
                                                     uint64_t* __restrict__ bits) {
    int p2 = blockIdx.x * 256 + threadIdx.x;
    int n = p2 / (HW / 2);
    int r2 = p2 - n * (HW / 2);
    const float2* xp = (const float2*)(x + (size_t)n * CC * HW) + r2;
    uint64_t b0 = 0, b1 = 0;
#pragma unroll 16
    for (int c = 0; c < 64; c++) {
        float2 v = xp[(size_t)c * (HW / 2)];
        b0 |= (uint64_t)(v.x > 0.0f) << c;
        b1 |= (uint64_t)(v.y > 0.0f) << c;
    }
    ulonglong2 pr;
    pr.x = b0; pr.y = b1;
    *((ulonglong2*)(bits + (size_t)n * HW) + r2) = pr;
}

__global__ __launch_bounds__(256) void stats3_kernel(const uint64_t* __restrict__ bits,
                                                     const uint64_t* __restrict__ wbits,
                                                     int* __restrict__ ch_sum,
                                                     unsigned long long* __restrict__ ch_sumsq) {
    __shared__ uint64_t rowbuf[4][3][58];
    __shared__ int redS[4][64];
    __shared__ int redQ[4][64];
    int tid = threadIdx.x;
    int wave = tid >> 6, lane = tid & 63;
    int Wid = blockIdx.x * 4 + wave;
    int n = __builtin_amdgcn_readfirstlane(Wid / 224);
    int rem = Wid - n * 224;
    int h = __builtin_amdgcn_readfirstlane(rem >> 1);
    int c0 = __builtin_amdgcn_readfirstlane((rem & 1) * 56);
    const uint64_t* bp = bits + (size_t)n * HW;

    for (int e = lane; e < 3 * 58; e += 64) {
        int t = e / 58, c = e - t * 58;
        int hh = h - 1 + t, ww = c0 - 1 + c;
        uint64_t v = 0;
        if (hh >= 0 && hh < HH && ww >= 0 && ww < WW) v = bp[hh * WW + ww];
        rowbuf[wave][t][c] = v;
    }
    WRegs W;
    load_wregs(W, wbits, lane, h);
    __syncthreads();

    const uint64_t(*rb)[58] = rowbuf[wave];
    int s1 = 0, s2 = 0;
    uint64_t win[3][3];
    for (int j0 = 0; j0 < 56; j0 += 14) {
#pragma unroll
        for (int rr = 0; rr < 3; rr++) { win[0][rr] = rb[rr][j0]; win[1][rr] = rb[rr][j0 + 1]; }
#pragma unroll
        for (int j = 0; j < 14; j++) {
#pragma unroll
            for (int rr = 0; rr < 3; rr++) win[(j + 2) % 3][rr] = rb[rr][j0 + j + 2];
            int S = conv_px(win[j % 3], win[(j + 1) % 3], win[(j + 2) % 3], W);
            int wpx = c0 + j0 + j;
            if (wpx == 0) S -= W.dL;
            if (wpx == WW - 1) S -= W.dR;
            s1 += S;
            s2 += S * S;
        }
    }
    redS[wave][lane] = s1;
    redQ[wave][lane] = s2;
    __syncthreads();
    if (tid < 64) {
        int t1 = redS[0][tid] + redS[1][tid] + redS[2][tid] + redS[3][tid];
        int t2 = redQ[0][tid] + redQ[1][tid] + redQ[2][tid] + redQ[3][tid];
        atomicAdd(&ch_sum[tid], t1);
        atomicAdd(&ch_sumsq[tid], (unsigned long long)(long long)t2);
    }
}

__global__ void bnprep_kernel(const int* __restrict__ ch_sum,
                              const unsigned long long* __restrict__ ch_sumsq,
                              const float* __restrict__ wscale,
                              const float* __restrict__ gamma,
                              const float* __restrict__ beta,
                              const uint64_t* __restrict__ wbits,
                              float* __restrict__ A2, float* __restrict__ B2) {
    int o = threadIdx.x;
    double P = (double)NHW;
    double meanS = (double)ch_sum[o] / P;
    double e2 = (double)ch_sumsq[o] / P;
    double varS = e2 - meanS * meanS;
    double sc = (double)wscale[o];
    double mean_y = sc * meanS;
    double var_y = sc * sc * varS;
    double inv = (double)gamma[o] / sqrt(var_y + 1e-5);
    float a = (float)(sc * inv);
    float b = (float)((double)beta[o] - mean_y * inv);
    A2[o] = -2.0f * a;
    int tc[9];
#pragma unroll
    for (int t = 0; t < 9; t++) tc[t] = 64 - 2 * (int)__builtin_popcountll(wbits[o * 9 + t]);
#pragma unroll
    for (int f = 0; f < 16; f++) {
        int corr = 0;
#pragma unroll
        for (int t = 0; t < 9; t++) {
            int r = t / 3, c = t % 3;
            bool pad = ((f & 1) && r == 0) || ((f & 2) && r == 2) ||
                       ((f & 4) && c == 0) || ((f & 8) && c == 2);
            if (pad) corr += tc[t];
        }
        B2[f * 64 + o] = (float)(576 - corr) * a + b;
    }
}

__global__ __launch_bounds__(256) void final4_kernel(const uint64_t* __restrict__ bits,
                                                     const uint64_t* __restrict__ wbits,
                                                     const float* __restrict__ A2,
                                                     const float* __restrict__ B2,
                                                     const float* __restrict__ x,
                                                     float* __restrict__ out) {
    __shared__ float b2s[16][65];
    int tid = threadIdx.x;
    for (int e = tid; e < 16 * 64; e += 256) b2s[e >> 6][e & 63] = B2[e];
    __syncthreads();

    int wave = tid >> 6, lane = tid & 63;
    int Wid = blockIdx.x * 4 + wave;
    int n = __builtin_amdgcn_readfirstlane(Wid / 196);
    int p = (Wid - n * 196) * 64 + lane;
    int h = p / WW;
    int w = p - h * WW;

    const uint64_t* bp = bits + (size_t)n * HW;
    uint64_t win[9];
#pragma unroll
    for (int t = 0; t < 9; t++) {
        int hh = h + (t / 3) - 1;
        int ww = w + (t % 3) - 1;
        bool valid = (hh >= 0) && (hh < HH) && (ww >= 0) && (ww < WW);
        int hc = hh < 0 ? 0 : (hh > HH - 1 ? HH - 1 : hh);
        int wc = ww < 0 ? 0 : (ww > WW - 1 ? WW - 1 : ww);
        uint64_t v = bp[hc * WW + wc];
        win[t] = valid ? v : 0ull;
    }
    int f = (h == 0 ? 1 : 0) | (h == HH - 1 ? 2 : 0) | (w == 0 ? 4 : 0) | (w == WW - 1 ? 8 : 0);
    const float* b2row = &b2s[f][0];

    uint32_t pcp[32];
#pragma unroll
    for (int o2 = 0; o2 < 32; o2++) {
        const uint64_t* wp = wbits + (o2 * 2) * 9;
        int pcA = 0, pcB = 0;
#pragma unroll
        for (int t = 0; t < 9; t++) {
            pcA += (int)__builtin_popcountll(win[t] ^ wp[t]);
            pcB += (int)__builtin_popcountll(win[t] ^ wp[t + 9]);
        }
        pcp[o2] = (uint32_t)pcA | ((uint32_t)pcB << 16);
    }

    const float* xb = x + (size_t)n * CC * HW + p;
    float* ob = out + (size_t)n * CC * HW + p;
#pragma unroll
    for (int o2 = 0; o2 < 32; o2++) {
        int o0 = o2 * 2, o1 = o2 * 2 + 1;
        float pc0 = (float)(int)(pcp[o2] & 0xffffu);
        float pc1 = (float)(int)(pcp[o2] >> 16);
        float y0 = fmaf(pc0, A2[o0], b2row[o0]) + xb[(size_t)o0 * HW];
        float y1 = fmaf(pc1, A2[o1], b2row[o1]) + xb[(size_t)o1 * HW];
        __builtin_nontemporal_store(y0, &ob[(size_t)o0 * HW]);
        __builtin_nontemporal_store(y1, &ob[(size_t)o1 * HW]);
    }
}

extern "C" void kernel_launch(void* const* d_in, const int* in_sizes, int n_in,
                              void* d_out, int out_size, void* d_ws, size_t ws_size,
                              hipStream_t stream) {
    const float* x     = (const float*)d_in[0];
    const float* wflat = (const float*)d_in[1];
    const float* gamma = (const float*)d_in[2];
    const float* beta  = (const float*)d_in[3];
    float* out = (float*)d_out;

    char* ws = (char*)d_ws;
    uint64_t* bits  = (uint64_t*)ws;                          // 401408*8 = 3,211,264 B
    uint64_t* wbits = (uint64_t*)(ws + 3211264);              // 576*8 = 4608 B
    float* wscale   = (float*)(ws + 3215872);                 // 256 B
    int* ch_sum     = (int*)(ws + 3216128);                   // 256 B
    unsigned long long* ch_sumsq = (unsigned long long*)(ws + 3216384); // 512 B
    float* A2       = (float*)(ws + 3216896);                 // 256 B
    float* B2       = (float*)(ws + 3217152);                 // 16*64*4 = 4096 B

    void* args[] = { (void*)&x, (void*)&wflat, (void*)&gamma, (void*)&beta, (void*)&out,
                     (void*)&bits, (void*)&wbits, (void*)&wscale, (void*)&ch_sum, (void*)&ch_sumsq };
    hipError_t err = hipLaunchCooperativeKernel((const void*)mega_kernel,
                                                dim3(GRID), dim3(256), args, 0, stream);
    if (err != hipSuccess) {
        // fallback: proven 5-kernel pipeline
        wpack_kernel<<<64, 64, 0, stream>>>(wflat, wbits, wscale, ch_sum, ch_sumsq);
        xpack2_kernel<<<NHW / 2 / 256, 256, 0, stream>>>(x, bits);
        stats3_kernel<<<NB * HH * 2 / 4, 256, 0, stream>>>(bits, wbits, ch_sum, ch_sumsq);
        bnprep_kernel<<<1, 64, 0, stream>>>(ch_sum, ch_sumsq, wscale, gamma, beta, wbits, A2, B2);
        final4_kernel<<<NB * HW / 64 / 4, 256, 0, stream>>>(bits, wbits, A2, B2, x, out);
    }
}

// Round 5
// 735.859 us; speedup vs baseline: 1.1958x; 1.1958x over previous
//
#include <hip/hip_runtime.h>
#include <hip/hip_cooperative_groups.h>
#include <stdint.h>

namespace cg = cooperative_groups;

#define NB 32
#define CC 64
#define HH 112
#define WW 112
#define HW (HH * WW)            // 12544
#define NHW (NB * HW)           // 401408

// ---- shared helpers ----
struct WRegs {
    uint64_t w[9];
    int corrMid, dL, dR;
};

__device__ __forceinline__ void load_wregs(WRegs& W, const uint64_t* __restrict__ wbits,
                                           int lane, int h) {
    int tc[9];
#pragma unroll
    for (int t = 0; t < 9; t++) {
        W.w[t] = wbits[lane * 9 + t];
        tc[t] = 64 - 2 * (int)__builtin_popcountll(W.w[t]);
    }
    W.corrMid = 0;
    int oL = 0, oR = 0;
    if (h == 0)      { W.corrMid = tc[0] + tc[1] + tc[2]; oL = tc[0]; oR = tc[2]; }
    if (h == HH - 1) { W.corrMid = tc[6] + tc[7] + tc[8]; oL = tc[6]; oR = tc[8]; }
    W.dL = tc[0] + tc[3] + tc[6] - oL;
    W.dR = tc[2] + tc[5] + tc[8] - oR;
}

__device__ __forceinline__ int conv_px(const uint64_t l[3], const uint64_t m[3],
                                       const uint64_t r[3], const WRegs& W) {
    int pc = 0;
#pragma unroll
    for (int rr = 0; rr < 3; rr++) {
        pc += (int)__builtin_popcountll(l[rr] ^ W.w[rr * 3 + 0]);
        pc += (int)__builtin_popcountll(m[rr] ^ W.w[rr * 3 + 1]);
        pc += (int)__builtin_popcountll(r[rr] ^ W.w[rr * 3 + 2]);
    }
    return 576 - 2 * pc - W.corrMid;
}

// ======================= MEGA KERNEL (cooperative) =======================
// min-waves/EU = 2 -> VGPR budget 256 (NOT 64: round-4's (256,4) bound caused
// massive scratch spills, +1GB HBM traffic). Grid chosen at launch from the
// occupancy query so cooperative co-residency is always valid.
__global__ __launch_bounds__(256, 2) void mega_kernel(
        const float* __restrict__ x, const float* __restrict__ wflat,
        const float* __restrict__ gamma, const float* __restrict__ beta,
        float* __restrict__ out,
        uint64_t* __restrict__ bits, uint64_t* __restrict__ wbits,
        float* __restrict__ wscale, int* __restrict__ ch_sum,
        unsigned long long* __restrict__ ch_sumsq) {
    cg::grid_group grid = cg::this_grid();

    __shared__ uint64_t rowbuf[4][3][58];
    __shared__ int redS[4][64];
    __shared__ int redQ[4][64];
    __shared__ float b2s[16][65];
    __shared__ float A2s[64];

    int tid = threadIdx.x;
    int wave = tid >> 6, lane = tid & 63;
    int bid = blockIdx.x;
    int nblk = gridDim.x;

    // ---------- phase A: xpack (vb 0..783) + wpack (vb 784..847, wave 0)
    for (int vb = bid; vb < 848; vb += nblk) {
        if (vb < 784) {
            int p2 = vb * 256 + tid;                     // < NHW/2 exactly
            int n = p2 / (HW / 2);
            int r2 = p2 - n * (HW / 2);
            const float2* xp = (const float2*)(x + (size_t)n * CC * HW) + r2;
            uint64_t b0 = 0, b1 = 0;
#pragma unroll 16
            for (int c = 0; c < 64; c++) {
                float2 v = xp[(size_t)c * (HW / 2)];
                b0 |= (uint64_t)(v.x > 0.0f) << c;
                b1 |= (uint64_t)(v.y > 0.0f) << c;
            }
            ulonglong2 pr;
            pr.x = b0; pr.y = b1;
            *((ulonglong2*)(bits + (size_t)n * HW) + r2) = pr;
        } else if (wave == 0) {
            int o = vb - 784;                            // output channel
            int i = lane;                                // input channel
            const float* wp = wflat + (size_t)(o * 64 + i) * 9;
            float w[9];
            float asum = 0.f;
#pragma unroll
            for (int t = 0; t < 9; t++) { w[t] = wp[t]; asum += fabsf(w[t]); }
#pragma unroll
            for (int s = 32; s > 0; s >>= 1) asum += __shfl_xor(asum, s, 64);
            float scale = asum * (1.0f / 576.0f);
            uint64_t b[9];
#pragma unroll
            for (int t = 0; t < 9; t++) b[t] = __ballot(w[t] >= 0.0f);
            if (i == 0) {
#pragma unroll
                for (int t = 0; t < 9; t++) wbits[o * 9 + t] = b[t];
                wscale[o] = scale;
                ch_sum[o] = 0;
                ch_sumsq[o] = 0ull;
            }
        }
    }
    grid.sync();

    // ---------- phase B: stats (1792 virtual blocks, 4 half-row waves each)
    for (int vb = bid; vb < 1792; vb += nblk) {
        int Wid = vb * 4 + wave;                      // < 7168
        int n = __builtin_amdgcn_readfirstlane(Wid / 224);
        int rem = Wid - n * 224;
        int h = __builtin_amdgcn_readfirstlane(rem >> 1);
        int c0 = __builtin_amdgcn_readfirstlane((rem & 1) * 56);
        const uint64_t* bp = bits + (size_t)n * HW;

        for (int e = lane; e < 3 * 58; e += 64) {
            int t = e / 58, c = e - t * 58;
            int hh = h - 1 + t, ww = c0 - 1 + c;
            uint64_t v = 0;
            if (hh >= 0 && hh < HH && ww >= 0 && ww < WW) v = bp[hh * WW + ww];
            rowbuf[wave][t][c] = v;
        }
        WRegs W;
        load_wregs(W, wbits, lane, h);
        __syncthreads();

        const uint64_t(*rb)[58] = rowbuf[wave];
        int s1 = 0, s2 = 0;
        uint64_t win[3][3];
        for (int j0 = 0; j0 < 56; j0 += 14) {
#pragma unroll
            for (int rr = 0; rr < 3; rr++) { win[0][rr] = rb[rr][j0]; win[1][rr] = rb[rr][j0 + 1]; }
#pragma unroll
            for (int j = 0; j < 14; j++) {
#pragma unroll
                for (int rr = 0; rr < 3; rr++) win[(j + 2) % 3][rr] = rb[rr][j0 + j + 2];
                int S = conv_px(win[j % 3], win[(j + 1) % 3], win[(j + 2) % 3], W);
                int wpx = c0 + j0 + j;
                if (wpx == 0) S -= W.dL;
                if (wpx == WW - 1) S -= W.dR;
                s1 += S;
                s2 += S * S;
            }
        }
        redS[wave][lane] = s1;
        redQ[wave][lane] = s2;
        __syncthreads();
        if (tid < 64) {
            int t1 = redS[0][tid] + redS[1][tid] + redS[2][tid] + redS[3][tid];
            int t2 = redQ[0][tid] + redQ[1][tid] + redQ[2][tid] + redQ[3][tid];
            atomicAdd(&ch_sum[tid], t1);
            atomicAdd(&ch_sumsq[tid], (unsigned long long)(long long)t2);
        }
        __syncthreads();
    }
    grid.sync();

    // ---------- bnprep: every block computes A2/B2 redundantly into LDS
    if (tid < 64) {
        int o = tid;
        double P = (double)NHW;
        double meanS = (double)ch_sum[o] / P;
        double e2 = (double)ch_sumsq[o] / P;
        double varS = e2 - meanS * meanS;
        double sc = (double)wscale[o];
        double mean_y = sc * meanS;
        double var_y = sc * sc * varS;
        double inv = (double)gamma[o] / sqrt(var_y + 1e-5);
        float a = (float)(sc * inv);
        float b = (float)((double)beta[o] - mean_y * inv);
        A2s[o] = -2.0f * a;
        int tc[9];
#pragma unroll
        for (int t = 0; t < 9; t++) tc[t] = 64 - 2 * (int)__builtin_popcountll(wbits[o * 9 + t]);
#pragma unroll
        for (int f = 0; f < 16; f++) {
            int corr = 0;
#pragma unroll
            for (int t = 0; t < 9; t++) {
                int r = t / 3, c = t % 3;
                bool pad = ((f & 1) && r == 0) || ((f & 2) && r == 2) ||
                           ((f & 4) && c == 0) || ((f & 8) && c == 2);
                if (pad) corr += tc[t];
            }
            b2s[f][o] = (float)(576 - corr) * a + b;
        }
    }
    __syncthreads();

    // ---------- phase C: final conv + BN + residual (1568 virtual blocks)
    for (int vb = bid; vb < 1568; vb += nblk) {
        int Wid = vb * 4 + wave;                      // < 6272
        int n = __builtin_amdgcn_readfirstlane(Wid / 196);
        int p = (Wid - n * 196) * 64 + lane;          // pixel in image
        int h = p / WW;
        int w = p - h * WW;

        const uint64_t* bp = bits + (size_t)n * HW;
        uint64_t win[9];
#pragma unroll
        for (int t = 0; t < 9; t++) {
            int hh = h + (t / 3) - 1;
            int ww = w + (t % 3) - 1;
            bool valid = (hh >= 0) && (hh < HH) && (ww >= 0) && (ww < WW);
            int hc = hh < 0 ? 0 : (hh > HH - 1 ? HH - 1 : hh);
            int wc = ww < 0 ? 0 : (ww > WW - 1 ? WW - 1 : ww);
            uint64_t v = bp[hc * WW + wc];
            win[t] = valid ? v : 0ull;
        }
        int f = (h == 0 ? 1 : 0) | (h == HH - 1 ? 2 : 0) | (w == 0 ? 4 : 0) | (w == WW - 1 ? 8 : 0);
        const float* b2row = &b2s[f][0];

        uint32_t pcp[32];
#pragma unroll
        for (int o2 = 0; o2 < 32; o2++) {
            const uint64_t* wp = wbits + (o2 * 2) * 9;   // wave-uniform -> scalar loads
            int pcA = 0, pcB = 0;
#pragma unroll
            for (int t = 0; t < 9; t++) {
                pcA += (int)__builtin_popcountll(win[t] ^ wp[t]);
                pcB += (int)__builtin_popcountll(win[t] ^ wp[t + 9]);
            }
            pcp[o2] = (uint32_t)pcA | ((uint32_t)pcB << 16);
        }

        const float* xb = x + (size_t)n * CC * HW + p;
        float* ob = out + (size_t)n * CC * HW + p;
#pragma unroll
        for (int o2 = 0; o2 < 32; o2++) {
            int o0 = o2 * 2, o1 = o2 * 2 + 1;
            float pc0 = (float)(int)(pcp[o2] & 0xffffu);
            float pc1 = (float)(int)(pcp[o2] >> 16);
            float y0 = fmaf(pc0, A2s[o0], b2row[o0]) + xb[(size_t)o0 * HW];
            float y1 = fmaf(pc1, A2s[o1], b2row[o1]) + xb[(size_t)o1 * HW];
            __builtin_nontemporal_store(y0, &ob[(size_t)o0 * HW]);
            __builtin_nontemporal_store(y1, &ob[(size_t)o1 * HW]);
        }
    }
}

// ======================= fallback path (proven 5-kernel pipeline) =======================
__global__ void wpack_kernel(const float* __restrict__ wflat,
                             uint64_t* __restrict__ wbits,
                             float* __restrict__ wscale,
                             int* __restrict__ ch_sum,
                             unsigned long long* __restrict__ ch_sumsq) {
    int o = blockIdx.x;
    int i = threadIdx.x;
    const float* wp = wflat + (size_t)(o * 64 + i) * 9;
    float w[9];
    float asum = 0.f;
#pragma unroll
    for (int t = 0; t < 9; t++) { w[t] = wp[t]; asum += fabsf(w[t]); }
#pragma unroll
    for (int s = 32; s > 0; s >>= 1) asum += __shfl_xor(asum, s, 64);
    float scale = asum * (1.0f / 576.0f);
    uint64_t b[9];
#pragma unroll
    for (int t = 0; t < 9; t++) b[t] = __ballot(w[t] >= 0.0f);
    if (i == 0) {
#pragma unroll
        for (int t = 0; t < 9; t++) wbits[o * 9 + t] = b[t];
        wscale[o] = scale;
        ch_sum[o] = 0;
        ch_sumsq[o] = 0ull;
    }
}

__global__ __launch_bounds__(256) void xpack2_kernel(const float* __restrict__ x,
                                                     uint64_t* __restrict__ bits) {
    int p2 = blockIdx.x * 256 + threadIdx.x;
    int n = p2 / (HW / 2);
    int r2 = p2 - n * (HW / 2);
    const float2* xp = (const float2*)(x + (size_t)n * CC * HW) + r2;
    uint64_t b0 = 0, b1 = 0;
#pragma unroll 16
    for (int c = 0; c < 64; c++) {
        float2 v = xp[(size_t)c * (HW / 2)];
        b0 |= (uint64_t)(v.x > 0.0f) << c;
        b1 |= (uint64_t)(v.y > 0.0f) << c;
    }
    ulonglong2 pr;
    pr.x = b0; pr.y = b1;
    *((ulonglong2*)(bits + (size_t)n * HW) + r2) = pr;
}

__global__ __launch_bounds__(256) void stats3_kernel(const uint64_t* __restrict__ bits,
                                                     const uint64_t* __restrict__ wbits,
                                                     int* __restrict__ ch_sum,
                                                     unsigned long long* __restrict__ ch_sumsq) {
    __shared__ uint64_t rowbuf[4][3][58];
    __shared__ int redS[4][64];
    __shared__ int redQ[4][64];
    int tid = threadIdx.x;
    int wave = tid >> 6, lane = tid & 63;
    int Wid = blockIdx.x * 4 + wave;
    int n = __builtin_amdgcn_readfirstlane(Wid / 224);
    int rem = Wid - n * 224;
    int h = __builtin_amdgcn_readfirstlane(rem >> 1);
    int c0 = __builtin_amdgcn_readfirstlane((rem & 1) * 56);
    const uint64_t* bp = bits + (size_t)n * HW;

    for (int e = lane; e < 3 * 58; e += 64) {
        int t = e / 58, c = e - t * 58;
        int hh = h - 1 + t, ww = c0 - 1 + c;
        uint64_t v = 0;
        if (hh >= 0 && hh < HH && ww >= 0 && ww < WW) v = bp[hh * WW + ww];
        rowbuf[wave][t][c] = v;
    }
    WRegs W;
    load_wregs(W, wbits, lane, h);
    __syncthreads();

    const uint64_t(*rb)[58] = rowbuf[wave];
    int s1 = 0, s2 = 0;
    uint64_t win[3][3];
    for (int j0 = 0; j0 < 56; j0 += 14) {
#pragma unroll
        for (int rr = 0; rr < 3; rr++) { win[0][rr] = rb[rr][j0]; win[1][rr] = rb[rr][j0 + 1]; }
#pragma unroll
        for (int j = 0; j < 14; j++) {
#pragma unroll
            for (int rr = 0; rr < 3; rr++) win[(j + 2) % 3][rr] = rb[rr][j0 + j + 2];
            int S = conv_px(win[j % 3], win[(j + 1) % 3], win[(j + 2) % 3], W);
            int wpx = c0 + j0 + j;
            if (wpx == 0) S -= W.dL;
            if (wpx == WW - 1) S -= W.dR;
            s1 += S;
            s2 += S * S;
        }
    }
    redS[wave][lane] = s1;
    redQ[wave][lane] = s2;
    __syncthreads();
    if (tid < 64) {
        int t1 = redS[0][tid] + redS[1][tid] + redS[2][tid] + redS[3][tid];
        int t2 = redQ[0][tid] + redQ[1][tid] + redQ[2][tid] + redQ[3][tid];
        atomicAdd(&ch_sum[tid], t1);
        atomicAdd(&ch_sumsq[tid], (unsigned long long)(long long)t2);
    }
}

__global__ void bnprep_kernel(const int* __restrict__ ch_sum,
                              const unsigned long long* __restrict__ ch_sumsq,
                              const float* __restrict__ wscale,
                              const float* __restrict__ gamma,
                              const float* __restrict__ beta,
                              const uint64_t* __restrict__ wbits,
                              float* __restrict__ A2, float* __restrict__ B2) {
    int o = threadIdx.x;
    double P = (double)NHW;
    double meanS = (double)ch_sum[o] / P;
    double e2 = (double)ch_sumsq[o] / P;
    double varS = e2 - meanS * meanS;
    double sc = (double)wscale[o];
    double mean_y = sc * meanS;
    double var_y = sc * sc * varS;
    double inv = (double)gamma[o] / sqrt(var_y + 1e-5);
    float a = (float)(sc * inv);
    float b = (float)((double)beta[o] - mean_y * inv);
    A2[o] = -2.0f * a;
    int tc[9];
#pragma unroll
    for (int t = 0; t < 9; t++) tc[t] = 64 - 2 * (int)__builtin_popcountll(wbits[o * 9 + t]);
#pragma unroll
    for (int f = 0; f < 16; f++) {
        int corr = 0;
#pragma unroll
        for (int t = 0; t < 9; t++) {
            int r = t / 3, c = t % 3;
            bool pad = ((f & 1) && r == 0) || ((f & 2) && r == 2) ||
                       ((f & 4) && c == 0) || ((f & 8) && c == 2);
            if (pad) corr += tc[t];
        }
        B2[f * 64 + o] = (float)(576 - corr) * a + b;
    }
}

__global__ __launch_bounds__(256) void final4_kernel(const uint64_t* __restrict__ bits,
                                                     const uint64_t* __restrict__ wbits,
                                                     const float* __restrict__ A2,
                                                     const float* __restrict__ B2,
                                                     const float* __restrict__ x,
                                                     float* __restrict__ out) {
    __shared__ float b2s[16][65];
    int tid = threadIdx.x;
    for (int e = tid; e < 16 * 64; e += 256) b2s[e >> 6][e & 63] = B2[e];
    __syncthreads();

    int wave = tid >> 6, lane = tid & 63;
    int Wid = blockIdx.x * 4 + wave;
    int n = __builtin_amdgcn_readfirstlane(Wid / 196);
    int p = (Wid - n * 196) * 64 + lane;
    int h = p / WW;
    int w = p - h * WW;

    const uint64_t* bp = bits + (size_t)n * HW;
    uint64_t win[9];
#pragma unroll
    for (int t = 0; t < 9; t++) {
        int hh = h + (t / 3) - 1;
        int ww = w + (t % 3) - 1;
        bool valid = (hh >= 0) && (hh < HH) && (ww >= 0) && (ww < WW);
        int hc = hh < 0 ? 0 : (hh > HH - 1 ? HH - 1 : hh);
        int wc = ww < 0 ? 0 : (ww > WW - 1 ? WW - 1 : ww);
        uint64_t v = bp[hc * WW + wc];
        win[t] = valid ? v : 0ull;
    }
    int f = (h == 0 ? 1 : 0) | (h == HH - 1 ? 2 : 0) | (w == 0 ? 4 : 0) | (w == WW - 1 ? 8 : 0);
    const float* b2row = &b2s[f][0];

    uint32_t pcp[32];
#pragma unroll
    for (int o2 = 0; o2 < 32; o2++) {
        const uint64_t* wp = wbits + (o2 * 2) * 9;
        int pcA = 0, pcB = 0;
#pragma unroll
        for (int t = 0; t < 9; t++) {
            pcA += (int)__builtin_popcountll(win[t] ^ wp[t]);
            pcB += (int)__builtin_popcountll(win[t] ^ wp[t + 9]);
        }
        pcp[o2] = (uint32_t)pcA | ((uint32_t)pcB << 16);
    }

    const float* xb = x + (size_t)n * CC * HW + p;
    float* ob = out + (size_t)n * CC * HW + p;
#pragma unroll
    for (int o2 = 0; o2 < 32; o2++) {
        int o0 = o2 * 2, o1 = o2 * 2 + 1;
        float pc0 = (float)(int)(pcp[o2] & 0xffffu);
        float pc1 = (float)(int)(pcp[o2] >> 16);
        float y0 = fmaf(pc0, A2[o0], b2row[o0]) + xb[(size_t)o0 * HW];
        float y1 = fmaf(pc1, A2[o1], b2row[o1]) + xb[(size_t)o1 * HW];
        __builtin_nontemporal_store(y0, &ob[(size_t)o0 * HW]);
        __builtin_nontemporal_store(y1, &ob[(size_t)o1 * HW]);
    }
}

extern "C" void kernel_launch(void* const* d_in, const int* in_sizes, int n_in,
                              void* d_out, int out_size, void* d_ws, size_t ws_size,
                              hipStream_t stream) {
    const float* x     = (const float*)d_in[0];
    const float* wflat = (const float*)d_in[1];
    const float* gamma = (const float*)d_in[2];
    const float* beta  = (const float*)d_in[3];
    float* out = (float*)d_out;

    char* ws = (char*)d_ws;
    uint64_t* bits  = (uint64_t*)ws;                          // 401408*8 = 3,211,264 B
    uint64_t* wbits = (uint64_t*)(ws + 3211264);              // 576*8 = 4608 B
    float* wscale   = (float*)(ws + 3215872);                 // 256 B
    int* ch_sum     = (int*)(ws + 3216128);                   // 256 B
    unsigned long long* ch_sumsq = (unsigned long long*)(ws + 3216384); // 512 B
    float* A2       = (float*)(ws + 3216896);                 // 256 B
    float* B2       = (float*)(ws + 3217152);                 // 16*64*4 = 4096 B

    // Host-side occupancy query (graph-capture-safe): size the cooperative grid
    // to what is guaranteed co-resident. Cached after first call.
    static int coop_grid = -1;
    if (coop_grid < 0) {
        int maxBlocksPerCU = 0;
        hipError_t qerr = hipOccupancyMaxActiveBlocksPerMultiprocessor(
            &maxBlocksPerCU, (const void*)mega_kernel, 256, 0);
        if (qerr != hipSuccess || maxBlocksPerCU <= 0) {
            coop_grid = 0;  // fallback path
        } else {
            int g = maxBlocksPerCU * 256;   // 256 CUs
            coop_grid = g > 1024 ? 1024 : g;
        }
    }

    if (coop_grid > 0) {
        void* args[] = { (void*)&x, (void*)&wflat, (void*)&gamma, (void*)&beta, (void*)&out,
                         (void*)&bits, (void*)&wbits, (void*)&wscale, (void*)&ch_sum, (void*)&ch_sumsq };
        hipError_t err = hipLaunchCooperativeKernel((const void*)mega_kernel,
                                                    dim3(coop_grid), dim3(256), args, 0, stream);
        if (err == hipSuccess) return;
    }

    // fallback: proven 5-kernel pipeline
    wpack_kernel<<<64, 64, 0, stream>>>(wflat, wbits, wscale, ch_sum, ch_sumsq);
    xpack2_kernel<<<NHW / 2 / 256, 256, 0, stream>>>(x, bits);
    stats3_kernel<<<NB * HH * 2 / 4, 256, 0, stream>>>(bits, wbits, ch_sum, ch_sumsq);
    bnprep_kernel<<<1, 64, 0, stream>>>(ch_sum, ch_sumsq, wscale, gamma, beta, wbits, A2, B2);
    final4_kernel<<<NB * HW / 64 / 4, 256, 0, stream>>>(bits, wbits, A2, B2, x, out);
}

// Round 7
// 703.580 us; speedup vs baseline: 1.2507x; 1.0459x over previous
//
#include <hip/hip_runtime.h>
#include <stdint.h>

#define NB 32
#define CC 64
#define HH 112
#define WW 112
#define HW (HH * WW)            // 12544
#define NHW (NB * HW)           // 401408

// ---------------- kernel 1: xpack (blocks 0..783) + wpack (blocks 784..847)
__global__ __launch_bounds__(256) void pack_kernel(const float* __restrict__ x,
                                                   const float* __restrict__ wflat,
                                                   uint64_t* __restrict__ bits,
                                                   uint64_t* __restrict__ wbits,
                                                   float* __restrict__ wscale,
                                                   int* __restrict__ ch_sum,
                                                   unsigned long long* __restrict__ ch_sumsq) {
    int bid = blockIdx.x;
    int tid = threadIdx.x;
    if (bid < 784) {
        // ---- xpack: pack sign(x) bits per pixel over 64 channels (float2)
        int p2 = bid * 256 + tid;                  // pixel-pair index, < NHW/2 exactly
        int n = p2 / (HW / 2);
        int r2 = p2 - n * (HW / 2);
        const float2* xp = (const float2*)(x + (size_t)n * CC * HW) + r2;
        uint64_t b0 = 0, b1 = 0;
#pragma unroll 16
        for (int c = 0; c < 64; c++) {
            float2 v = xp[(size_t)c * (HW / 2)];
            b0 |= (uint64_t)(v.x > 0.0f) << c;
            b1 |= (uint64_t)(v.y > 0.0f) << c;
        }
        ulonglong2 pr;
        pr.x = b0; pr.y = b1;
        *((ulonglong2*)(bits + (size_t)n * HW) + r2) = pr;
    } else if (tid < 64) {
        // ---- wpack: binarize weights -> bits + scale; zero stat accumulators
        int o = bid - 784;       // output channel
        int i = tid;             // input channel (lane id, wave 0 fully active)
        const float* wp = wflat + (size_t)(o * 64 + i) * 9;
        float w[9];
        float asum = 0.f;
#pragma unroll
        for (int t = 0; t < 9; t++) { w[t] = wp[t]; asum += fabsf(w[t]); }
#pragma unroll
        for (int s = 32; s > 0; s >>= 1) asum += __shfl_xor(asum, s, 64);
        float scale = asum * (1.0f / 576.0f);
        uint64_t b[9];
#pragma unroll
        for (int t = 0; t < 9; t++) b[t] = __ballot(w[t] >= 0.0f);
        if (i == 0) {
#pragma unroll
            for (int t = 0; t < 9; t++) wbits[o * 9 + t] = b[t];
            wscale[o] = scale;
            ch_sum[o] = 0;
            ch_sumsq[o] = 0ull;
        }
    }
}

// ---- shared: load the 9-tap zero-padded bit window for this lane's pixel
__device__ __forceinline__ void load_window(uint64_t win[9], const uint64_t* __restrict__ bp,
                                            int h, int w) {
#pragma unroll
    for (int t = 0; t < 9; t++) {
        int hh = h + (t / 3) - 1;
        int ww = w + (t % 3) - 1;
        bool valid = (hh >= 0) && (hh < HH) && (ww >= 0) && (ww < WW);
        int hc = hh < 0 ? 0 : (hh > HH - 1 ? HH - 1 : hh);
        int wc = ww < 0 ? 0 : (ww > WW - 1 ? WW - 1 : ww);
        uint64_t v = bp[hc * WW + wc];
        win[t] = valid ? v : 0ull;
    }
}

// ---------------- kernel 2: stats — lane = pixel, wave owns 16 channels x 256 px.
// No LDS staging, no per-pixel syncs. S integer-exact: S = 576 - 2*pc - corr[f][o].
__global__ __launch_bounds__(256) void stats4_kernel(const uint64_t* __restrict__ bits,
                                                     const uint64_t* __restrict__ wbits,
                                                     int* __restrict__ ch_sum,
                                                     unsigned long long* __restrict__ ch_sumsq) {
    __shared__ int c2s[16][65];   // corr per (edge-flag, channel), padded
    int tid = threadIdx.x;
    int wave = tid >> 6, lane = tid & 63;

    if (tid < 64) {
        int o = tid;
        int tc[9];
#pragma unroll
        for (int t = 0; t < 9; t++) tc[t] = 64 - 2 * (int)__builtin_popcountll(wbits[o * 9 + t]);
#pragma unroll
        for (int f = 0; f < 16; f++) {
            int corr = 0;
#pragma unroll
            for (int t = 0; t < 9; t++) {
                int r = t / 3, c = t % 3;
                bool pad = ((f & 1) && r == 0) || ((f & 2) && r == 2) ||
                           ((f & 4) && c == 0) || ((f & 8) && c == 2);
                if (pad) corr += tc[t];
            }
            c2s[f][o] = corr;
        }
    }
    __syncthreads();

    int blk = blockIdx.x;                 // 1568 blocks; 49 blocks/image (49*256 = HW)
    int n = blk / 49;
    int poff = (blk - n * 49) * 256;
    const uint64_t* bp = bits + (size_t)n * HW;

    int s1[16], s2[16];
#pragma unroll
    for (int q = 0; q < 16; q++) { s1[q] = 0; s2[q] = 0; }

#pragma unroll 1
    for (int sub = 0; sub < 4; sub++) {
        int p = poff + sub * 64 + lane;
        int h = p / WW;
        int w = p - h * WW;
        uint64_t win[9];
        load_window(win, bp, h, w);
        int f = (h == 0 ? 1 : 0) | (h == HH - 1 ? 2 : 0) | (w == 0 ? 4 : 0) | (w == WW - 1 ? 8 : 0);
#pragma unroll
        for (int oq = 0; oq < 16; oq++) {
            int o = (wave << 4) + oq;
            const uint64_t* wp = wbits + o * 9;   // wave-uniform -> scalar loads
            int pc = 0;
#pragma unroll
            for (int t = 0; t < 9; t++) pc += (int)__builtin_popcountll(win[t] ^ wp[t]);
            int S = 576 - 2 * pc - c2s[f][o];
            s1[oq] += S;
            s2[oq] += S * S;                      // per-lane <= 4*576^2 = 1.33M, fits int
        }
    }

    // 64-lane butterfly reduce per owned channel; one atomic pair per (wave, channel)
#pragma unroll
    for (int oq = 0; oq < 16; oq++) {
        int r1 = s1[oq], r2 = s2[oq];
#pragma unroll
        for (int s = 32; s > 0; s >>= 1) {
            r1 += __shfl_xor(r1, s, 64);
            r2 += __shfl_xor(r2, s, 64);          // block-level <= 85M, fits int
        }
        if (lane == 0) {
            int o = (wave << 4) + oq;
            atomicAdd(&ch_sum[o], r1);
            atomicAdd(&ch_sumsq[o], (unsigned long long)(long long)r2);
        }
    }
}

// ---------------- kernel 3: bnprep preamble + conv + BN affine + residual
__global__ __launch_bounds__(256) void final5_kernel(const uint64_t* __restrict__ bits,
                                                     const uint64_t* __restrict__ wbits,
                                                     const int* __restrict__ ch_sum,
                                                     const unsigned long long* __restrict__ ch_sumsq,
                                                     const float* __restrict__ wscale,
                                                     const float* __restrict__ gamma,
                                                     const float* __restrict__ beta,
                                                     const float* __restrict__ x,
                                                     float* __restrict__ out) {
    __shared__ float b2s[16][65];
    __shared__ float A2s[64];
    int tid = threadIdx.x;

    // bnprep, computed redundantly per block (proven inside R5 mega phase C)
    if (tid < 64) {
        int o = tid;
        double P = (double)NHW;
        double meanS = (double)ch_sum[o] / P;
        double e2 = (double)ch_sumsq[o] / P;
        double varS = e2 - meanS * meanS;
        double sc = (double)wscale[o];
        double mean_y = sc * meanS;
        double var_y = sc * sc * varS;
        double inv = (double)gamma[o] / sqrt(var_y + 1e-5);
        float a = (float)(sc * inv);
        float b = (float)((double)beta[o] - mean_y * inv);
        A2s[o] = -2.0f * a;
        int tc[9];
#pragma unroll
        for (int t = 0; t < 9; t++) tc[t] = 64 - 2 * (int)__builtin_popcountll(wbits[o * 9 + t]);
#pragma unroll
        for (int f = 0; f < 16; f++) {
            int corr = 0;
#pragma unroll
            for (int t = 0; t < 9; t++) {
                int r = t / 3, c = t % 3;
                bool pad = ((f & 1) && r == 0) || ((f & 2) && r == 2) ||
                           ((f & 4) && c == 0) || ((f & 8) && c == 2);
                if (pad) corr += tc[t];
            }
            b2s[f][o] = (float)(576 - corr) * a + b;
        }
    }
    __syncthreads();

    int wave = tid >> 6, lane = tid & 63;
    int Wid = blockIdx.x * 4 + wave;              // < 6272 exact
    int n = __builtin_amdgcn_readfirstlane(Wid / 196);
    int p = (Wid - n * 196) * 64 + lane;          // pixel index within image
    int h = p / WW;
    int w = p - h * WW;

    const uint64_t* bp = bits + (size_t)n * HW;
    uint64_t win[9];
    load_window(win, bp, h, w);
    int f = (h == 0 ? 1 : 0) | (h == HH - 1 ? 2 : 0) | (w == 0 ? 4 : 0) | (w == WW - 1 ? 8 : 0);
    const float* b2row = &b2s[f][0];

    // phase 1: all popcounts, packed 2 channels per VGPR
    uint32_t pcp[32];
#pragma unroll
    for (int o2 = 0; o2 < 32; o2++) {
        const uint64_t* wp = wbits + (o2 * 2) * 9;   // wave-uniform -> scalar loads
        int pcA = 0, pcB = 0;
#pragma unroll
        for (int t = 0; t < 9; t++) {
            pcA += (int)__builtin_popcountll(win[t] ^ wp[t]);
            pcB += (int)__builtin_popcountll(win[t] ^ wp[t + 9]);
        }
        pcp[o2] = (uint32_t)pcA | ((uint32_t)pcB << 16);
    }

    // phase 2: independent load/fma/store per channel
    const float* xb = x + (size_t)n * CC * HW + p;
    float* ob = out + (size_t)n * CC * HW + p;
#pragma unroll
    for (int o2 = 0; o2 < 32; o2++) {
        int o0 = o2 * 2, o1 = o2 * 2 + 1;
        float pc0 = (float)(int)(pcp[o2] & 0xffffu);
        float pc1 = (float)(int)(pcp[o2] >> 16);
        float y0 = fmaf(pc0, A2s[o0], b2row[o0]) + xb[(size_t)o0 * HW];
        float y1 = fmaf(pc1, A2s[o1], b2row[o1]) + xb[(size_t)o1 * HW];
        __builtin_nontemporal_store(y0, &ob[(size_t)o0 * HW]);
        __builtin_nontemporal_store(y1, &ob[(size_t)o1 * HW]);
    }
}

extern "C" void kernel_launch(void* const* d_in, const int* in_sizes, int n_in,
                              void* d_out, int out_size, void* d_ws, size_t ws_size,
                              hipStream_t stream) {
    const float* x     = (const float*)d_in[0];
    const float* wflat = (const float*)d_in[1];
    const float* gamma = (const float*)d_in[2];
    const float* beta  = (const float*)d_in[3];
    float* out = (float*)d_out;

    char* ws = (char*)d_ws;
    uint64_t* bits  = (uint64_t*)ws;                          // 401408*8 = 3,211,264 B
    uint64_t* wbits = (uint64_t*)(ws + 3211264);              // 576*8 = 4608 B
    float* wscale   = (float*)(ws + 3215872);                 // 256 B
    int* ch_sum     = (int*)(ws + 3216128);                   // 256 B
    unsigned long long* ch_sumsq = (unsigned long long*)(ws + 3216384); // 512 B

    pack_kernel<<<848, 256, 0, stream>>>(x, wflat, bits, wbits, wscale, ch_sum, ch_sumsq);
    stats4_kernel<<<1568, 256, 0, stream>>>(bits, wbits, ch_sum, ch_sumsq);
    final5_kernel<<<NB * HW / 64 / 4, 256, 0, stream>>>(bits, wbits, ch_sum, ch_sumsq,
                                                        wscale, gamma, beta, x, out);
}

// Round 10
// 696.174 us; speedup vs baseline: 1.2640x; 1.0106x over previous
//
#include <hip/hip_runtime.h>
#include <stdint.h>

#define NB 32
#define CC 64
#define HH 112
#define WW 112
#define HW (HH * WW)            // 12544
#define NHW (NB * HW)           // 401408

// ---------------- kernel 1: xpack (blocks 0..783) + wpack (blocks 784..847)
__global__ __launch_bounds__(256) void pack_kernel(const float* __restrict__ x,
                                                   const float* __restrict__ wflat,
                                                   uint64_t* __restrict__ bits,
                                                   uint64_t* __restrict__ wbits,
                                                   float* __restrict__ wscale,
                                                   int* __restrict__ ch_sum,
                                                   unsigned long long* __restrict__ ch_sumsq) {
    int bid = blockIdx.x;
    int tid = threadIdx.x;
    if (bid < 784) {
        // ---- xpack: pack sign(x) bits per pixel over 64 channels (float2)
        int p2 = bid * 256 + tid;                  // pixel-pair index, < NHW/2 exactly
        int n = p2 / (HW / 2);
        int r2 = p2 - n * (HW / 2);
        const float2* xp = (const float2*)(x + (size_t)n * CC * HW) + r2;
        uint64_t b0 = 0, b1 = 0;
#pragma unroll 16
        for (int c = 0; c < 64; c++) {
            float2 v = xp[(size_t)c * (HW / 2)];
            b0 |= (uint64_t)(v.x > 0.0f) << c;
            b1 |= (uint64_t)(v.y > 0.0f) << c;
        }
        ulonglong2 pr;
        pr.x = b0; pr.y = b1;
        *((ulonglong2*)(bits + (size_t)n * HW) + r2) = pr;
    } else if (tid < 64) {
        // ---- wpack: binarize weights -> bits + scale; zero stat accumulators
        int o = bid - 784;       // output channel
        int i = tid;             // input channel (lane id, wave 0 fully active)
        const float* wp = wflat + (size_t)(o * 64 + i) * 9;
        float w[9];
        float asum = 0.f;
#pragma unroll
        for (int t = 0; t < 9; t++) { w[t] = wp[t]; asum += fabsf(w[t]); }
#pragma unroll
        for (int s = 32; s > 0; s >>= 1) asum += __shfl_xor(asum, s, 64);
        float scale = asum * (1.0f / 576.0f);
        uint64_t b[9];
#pragma unroll
        for (int t = 0; t < 9; t++) b[t] = __ballot(w[t] >= 0.0f);
        if (i == 0) {
#pragma unroll
            for (int t = 0; t < 9; t++) wbits[o * 9 + t] = b[t];
            wscale[o] = scale;
            ch_sum[o] = 0;
            ch_sumsq[o] = 0ull;
        }
    }
}

// ---- shared: load the 9-tap zero-padded bit window for this lane's pixel
__device__ __forceinline__ void load_window(uint64_t win[9], const uint64_t* __restrict__ bp,
                                            int h, int w) {
#pragma unroll
    for (int t = 0; t < 9; t++) {
        int hh = h + (t / 3) - 1;
        int ww = w + (t % 3) - 1;
        bool valid = (hh >= 0) && (hh < HH) && (ww >= 0) && (ww < WW);
        int hc = hh < 0 ? 0 : (hh > HH - 1 ? HH - 1 : hh);
        int wc = ww < 0 ? 0 : (ww > WW - 1 ? WW - 1 : ww);
        uint64_t v = bp[hc * WW + wc];
        win[t] = valid ? v : 0ull;
    }
}

// ---------------- kernel 2: stats — lane = pixel, wave owns 16 channels x 256 px.
// Weight pointers wave-uniform (s_load); windows preloaded into registers;
// channels outer so 9 scalar loads serve 4 pixels.
__global__ __launch_bounds__(256) void stats5_kernel(const uint64_t* __restrict__ bits,
                                                     const uint64_t* __restrict__ wbits,
                                                     int* __restrict__ ch_sum,
                                                     unsigned long long* __restrict__ ch_sumsq) {
    __shared__ int c2s[16][65];   // corr per (edge-flag, channel), padded
    int tid = threadIdx.x;
    int lane = tid & 63;

    if (tid < 64) {
        int o = tid;
        int tc[9];
#pragma unroll
        for (int t = 0; t < 9; t++) tc[t] = 64 - 2 * (int)__builtin_popcountll(wbits[o * 9 + t]);
#pragma unroll
        for (int f = 0; f < 16; f++) {
            int corr = 0;
#pragma unroll
            for (int t = 0; t < 9; t++) {
                int r = t / 3, c = t % 3;
                bool pad = ((f & 1) && r == 0) || ((f & 2) && r == 2) ||
                           ((f & 4) && c == 0) || ((f & 8) && c == 2);
                if (pad) corr += tc[t];
            }
            c2s[f][o] = corr;
        }
    }
    __syncthreads();

    int blk = blockIdx.x;                 // 1568 blocks; 49 blocks/image (49*256 = HW)
    int n = blk / 49;
    int poff = (blk - n * 49) * 256;
    const uint64_t* bp = bits + (size_t)n * HW;

    // SGPR-uniform channel base for this wave: 0,16,32,48
    int wavebase = __builtin_amdgcn_readfirstlane(tid >> 6) << 4;

    // preload this lane's 4 pixel-windows (4 x 9 u64 = 72 VGPRs) + edge flags
    uint64_t win4[4][9];
    int f4[4];
#pragma unroll
    for (int sub = 0; sub < 4; sub++) {
        int p = poff + sub * 64 + lane;
        int h = p / WW;
        int w = p - h * WW;
        load_window(win4[sub], bp, h, w);
        f4[sub] = (h == 0 ? 1 : 0) | (h == HH - 1 ? 2 : 0) | (w == 0 ? 4 : 0) | (w == WW - 1 ? 8 : 0);
    }

    for (int oq = 0; oq < 16; oq++) {
        int o = wavebase + oq;                       // SGPR
        const uint64_t* wp = wbits + o * 9;          // SGPR base -> s_load
        uint64_t wreg[9];
#pragma unroll
        for (int t = 0; t < 9; t++) wreg[t] = wp[t];

        int s1 = 0, s2 = 0;
#pragma unroll
        for (int sub = 0; sub < 4; sub++) {
            int pc = 0;
#pragma unroll
            for (int t = 0; t < 9; t++) pc += (int)__builtin_popcountll(win4[sub][t] ^ wreg[t]);
            int S = 576 - 2 * pc - c2s[f4[sub]][o];
            s1 += S;
            s2 += S * S;                             // per-lane <= 4*576^2 = 1.33M, fits int
        }
        // 64-lane butterfly; one atomic pair per (wave, channel)
#pragma unroll
        for (int s = 32; s > 0; s >>= 1) {
            s1 += __shfl_xor(s1, s, 64);
            s2 += __shfl_xor(s2, s, 64);             // block-level <= 85M, fits int
        }
        if (lane == 0) {
            atomicAdd(&ch_sum[o], s1);
            atomicAdd(&ch_sumsq[o], (unsigned long long)(long long)s2);
        }
    }
}

// ---------------- kernel 3: bnprep preamble + conv + BN affine + residual
__global__ __launch_bounds__(256) void final5_kernel(const uint64_t* __restrict__ bits,
                                                     const uint64_t* __restrict__ wbits,
                                                     const int* __restrict__ ch_sum,
                                                     const unsigned long long* __restrict__ ch_sumsq,
                                                     const float* __restrict__ wscale,
                                                     const float* __restrict__ gamma,
                                                     const float* __restrict__ beta,
                                                     const float* __restrict__ x,
                                                     float* __restrict__ out) {
    __shared__ float b2s[16][65];
    __shared__ float A2s[64];
    int tid = threadIdx.x;

    // bnprep, computed redundantly per block
    if (tid < 64) {
        int o = tid;
        double P = (double)NHW;
        double meanS = (double)ch_sum[o] / P;
        double e2 = (double)ch_sumsq[o] / P;
        double varS = e2 - meanS * meanS;
        double sc = (double)wscale[o];
        double mean_y = sc * meanS;
        double var_y = sc * sc * varS;
        double inv = (double)gamma[o] / sqrt(var_y + 1e-5);
        float a = (float)(sc * inv);
        float b = (float)((double)beta[o] - mean_y * inv);
        A2s[o] = -2.0f * a;
        int tc[9];
#pragma unroll
        for (int t = 0; t < 9; t++) tc[t] = 64 - 2 * (int)__builtin_popcountll(wbits[o * 9 + t]);
#pragma unroll
        for (int f = 0; f < 16; f++) {
            int corr = 0;
#pragma unroll
            for (int t = 0; t < 9; t++) {
                int r = t / 3, c = t % 3;
                bool pad = ((f & 1) && r == 0) || ((f & 2) && r == 2) ||
                           ((f & 4) && c == 0) || ((f & 8) && c == 2);
                if (pad) corr += tc[t];
            }
            b2s[f][o] = (float)(576 - corr) * a + b;
        }
    }
    __syncthreads();

    int wave = tid >> 6, lane = tid & 63;
    int Wid = blockIdx.x * 4 + wave;              // < 6272 exact
    int n = __builtin_amdgcn_readfirstlane(Wid / 196);
    int p = (Wid - n * 196) * 64 + lane;          // pixel index within image
    int h = p / WW;
    int w = p - h * WW;

    const uint64_t* bp = bits + (size_t)n * HW;
    uint64_t win[9];
    load_window(win, bp, h, w);
    int f = (h == 0 ? 1 : 0) | (h == HH - 1 ? 2 : 0) | (w == 0 ? 4 : 0) | (w == WW - 1 ? 8 : 0);
    const float* b2row = &b2s[f][0];

    // phase 1: all popcounts, packed 2 channels per VGPR
    uint32_t pcp[32];
#pragma unroll
    for (int o2 = 0; o2 < 32; o2++) {
        const uint64_t* wp = wbits + (o2 * 2) * 9;   // tid-independent -> s_load
        int pcA = 0, pcB = 0;
#pragma unroll
        for (int t = 0; t < 9; t++) {
            pcA += (int)__builtin_popcountll(win[t] ^ wp[t]);
            pcB += (int)__builtin_popcountll(win[t] ^ wp[t + 9]);
        }
        pcp[o2] = (uint32_t)pcA | ((uint32_t)pcB << 16);
    }

    // phase 2: independent load/fma/store per channel
    const float* xb = x + (size_t)n * CC * HW + p;
    float* ob = out + (size_t)n * CC * HW + p;
#pragma unroll
    for (int o2 = 0; o2 < 32; o2++) {
        int o0 = o2 * 2, o1 = o2 * 2 + 1;
        float pc0 = (float)(int)(pcp[o2] & 0xffffu);
        float pc1 = (float)(int)(pcp[o2] >> 16);
        float y0 = fmaf(pc0, A2s[o0], b2row[o0]) + xb[(size_t)o0 * HW];
        float y1 = fmaf(pc1, A2s[o1], b2row[o1]) + xb[(size_t)o1 * HW];
        __builtin_nontemporal_store(y0, &ob[(size_t)o0 * HW]);
        __builtin_nontemporal_store(y1, &ob[(size_t)o1 * HW]);
    }
}

extern "C" void kernel_launch(void* const* d_in, const int* in_sizes, int n_in,
                              void* d_out, int out_size, void* d_ws, size_t ws_size,
                              hipStream_t stream) {
    const float* x     = (const float*)d_in[0];
    const float* wflat = (const float*)d_in[1];
    const float* gamma = (const float*)d_in[2];
    const float* beta  = (const float*)d_in[3];
    float* out = (float*)d_out;

    char* ws = (char*)d_ws;
    uint64_t* bits  = (uint64_t*)ws;                          // 401408*8 = 3,211,264 B
    uint64_t* wbits = (uint64_t*)(ws + 3211264);              // 576*8 = 4608 B
    float* wscale   = (float*)(ws + 3215872);                 // 256 B
    int* ch_sum     = (int*)(ws + 3216128);                   // 256 B
    unsigned long long* ch_sumsq = (unsigned long long*)(ws + 3216384); // 512 B

    pack_kernel<<<848, 256, 0, stream>>>(x, wflat, bits, wbits, wscale, ch_sum, ch_sumsq);
    stats5_kernel<<<1568, 256, 0, stream>>>(bits, wbits, ch_sum, ch_sumsq);
    final5_kernel<<<NB * HW / 64 / 4, 256, 0, stream>>>(bits, wbits, ch_sum, ch_sumsq,
                                                        wscale, gamma, beta, x, out);
}